// Round 1
// 445.472 us; speedup vs baseline: 1.1724x; 1.1724x over previous
//
#include <hip/hip_runtime.h>

// out[B=16384, ONUM=512] = x[B, INUM=4096] @ wB[ONUM, INUM]^T, wB = (u < weight)
// v2: latency-bound fix — 512-thr blocks (16 waves/CU), double-buffered async
// prefetch (T3-minimal), XCD-chunked swizzle for x L2 reuse, B XOR-swizzle
// (pre-swizzled global_load_lds source) to kill the 16-way bank conflict.

#define M_DIM 16384
#define N_DIM 512
#define K_DIM 4096
#define BM 128
#define BN 128
#define BK 64
#define NT (K_DIM / BK)
#define THREADS 512

using bf16x8 = __attribute__((ext_vector_type(8))) short;
using f32x4  = __attribute__((ext_vector_type(4))) float;

typedef __attribute__((address_space(1))) const void glb_cv;
typedef __attribute__((address_space(3))) void lds_v;

__device__ __forceinline__ unsigned short f2bf(float f) {
    union { float f; unsigned int u; } v;
    v.f = f;
    unsigned int r = v.u + 0x7FFFu + ((v.u >> 16) & 1u);   // RNE
    return (unsigned short)(r >> 16);
}

// ---------------- binarize: wB[o,k] = (u < weight) ? 1.0bf16 : 0 ----------------
__global__ __launch_bounds__(256) void binarize_kernel(const float* __restrict__ w,
                                                       const float* __restrict__ u,
                                                       unsigned short* __restrict__ wb) {
    int i = (blockIdx.x * 256 + threadIdx.x) * 4;
    float4 wv = *(const float4*)(w + i);
    float4 uv = *(const float4*)(u + i);
    ushort4 o;
    o.x = (uv.x < wv.x) ? 0x3F80u : 0u;
    o.y = (uv.y < wv.y) ? 0x3F80u : 0u;
    o.z = (uv.z < wv.z) ? 0x3F80u : 0u;
    o.w = (uv.w < wv.w) ? 0x3F80u : 0u;
    *(ushort4*)(wb + i) = o;
}

// ---------------- GEMM: 128x128 tile, BK=64, 8 waves (4m x 2n), dbuf prefetch ----------------
__global__ __launch_bounds__(THREADS, 4) void gemm_bin_kernel(const float* __restrict__ x,
                                                              const unsigned short* __restrict__ wb,
                                                              float* __restrict__ out) {
    // A: padded rows (stride 144B, 16B-aligned) — reg-staged ds_write, pad OK.
    // B: linear (global_load_lds needs contiguous dest) — XOR-swizzled CONTENT:
    //    LDS 16B-chunk (row, c8) holds global chunk (row, c8 ^ (row&7)).
    __shared__ __attribute__((aligned(16))) unsigned short As[2][BM][72];
    __shared__ __attribute__((aligned(16))) unsigned short Bs[2][BN][BK];

    const int t    = threadIdx.x;
    const int lane = t & 63;
    const int wave = t >> 6;                       // 0..7

    // XCD-chunked swizzle: physical bid round-robins XCDs; give XCD q logical
    // blocks [q*64,(q+1)*64) so the 4 bn-sharers of each bm run on ONE XCD's L2.
    const int bid = blockIdx.x;                    // 512 blocks, 512%8==0
    const int swz = (bid & 7) * 64 + (bid >> 3);
    const int bn  = swz & 3;
    const int bm  = swz >> 2;

    const int wm = (wave >> 1) * 32;               // 4 waves along M
    const int wn = (wave & 1) * 64;                // 2 waves along N

    const int khi  = lane >> 4;                    // 0..3
    const int swzl = lane & 7;

    f32x4 acc[2][4] = {};

    // A staging map: thread t -> per j: row j*32 + (t>>4), col (t&15)*4 floats
    const int arow = t >> 4;                       // 0..31
    const int acol = (t & 15) * 4;
    const float* xg = x + (size_t)(bm * BM) * K_DIM;
    const unsigned short* wbg = wb + (size_t)(bn * BN) * K_DIM;

    float4 areg[4];

#define LOADA(k0)                                                          \
    _Pragma("unroll")                                                      \
    for (int j = 0; j < 4; ++j) {                                          \
        int r = j * 32 + arow;                                             \
        areg[j] = *(const float4*)(xg + (size_t)r * K_DIM + (k0) + acol);  \
    }

#define STOREA(b)                                                          \
    _Pragma("unroll")                                                      \
    for (int j = 0; j < 4; ++j) {                                          \
        int r = j * 32 + arow;                                             \
        ushort4 h;                                                         \
        h.x = f2bf(areg[j].x); h.y = f2bf(areg[j].y);                      \
        h.z = f2bf(areg[j].z); h.w = f2bf(areg[j].w);                      \
        *(ushort4*)(&As[b][r][acol]) = h;                                  \
    }

    // B: 128x64 bf16 = 16KB = 1024 x 16B chunks; 2 issues/thread.
    // Pre-swizzled SOURCE (rule 21): fetch global chunk (rb, c8 ^ (rb&7)).
#define GLLB(b, k0)                                                        \
    _Pragma("unroll")                                                      \
    for (int c = 0; c < 2; ++c) {                                          \
        int e  = c * THREADS + t;                                          \
        int rb = e >> 3;                                                   \
        int c8 = (e & 7) ^ (rb & 7);                                       \
        const unsigned short* gsrc = wbg + (size_t)rb * K_DIM + (k0) + c8 * 8; \
        unsigned short* ldst = (unsigned short*)&Bs[b][0][0] + (size_t)e * 8;  \
        __builtin_amdgcn_global_load_lds((glb_cv*)(const void*)gsrc,       \
                                         (lds_v*)(void*)ldst, 16, 0, 0);   \
    }

    // ---- prologue: stage tile 0 ----
    LOADA(0);
    GLLB(0, 0);
    STOREA(0);
    __syncthreads();

    int cur = 0;
    for (int kt = 0; kt < NT; ++kt) {
        const bool pf = (kt + 1 < NT);
        if (pf) {
            LOADA((kt + 1) * BK);        // A first: STOREA's vmcnt wait leaves B in flight
            GLLB(cur ^ 1, (kt + 1) * BK);
        }

        // ---- compute from buf[cur]: 2 k-steps of 32 ----
#pragma unroll
        for (int kk = 0; kk < 2; ++kk) {
            bf16x8 af[2], bfr[4];
#pragma unroll
            for (int i = 0; i < 2; ++i)
                af[i] = *(const bf16x8*)(&As[cur][wm + i * 16 + (lane & 15)][kk * 32 + khi * 8]);
#pragma unroll
            for (int j = 0; j < 4; ++j) {
                int row = wn + j * 16 + (lane & 15);   // row&7 == lane&7 == swzl
                int kc  = kk * 4 + khi;
                const char* p = (const char*)&Bs[cur][0][0] + row * (BK * 2) + ((kc ^ swzl) << 4);
                bfr[j] = *(const bf16x8*)p;
            }
#pragma unroll
            for (int i = 0; i < 2; ++i)
#pragma unroll
                for (int j = 0; j < 4; ++j)
                    acc[i][j] = __builtin_amdgcn_mfma_f32_16x16x32_bf16(af[i], bfr[j], acc[i][j], 0, 0, 0);
        }

        if (pf) { STOREA(cur ^ 1); }     // waits vmcnt for areg; gll B stays queued
        __syncthreads();                 // drains everything; next tile ready
        cur ^= 1;
    }

    // ---- epilogue: C/D layout col=lane&15, row=(lane>>4)*4+reg ----
    const int col0 = bn * BN + wn + (lane & 15);
    const int row0 = bm * BM + wm + khi * 4;
#pragma unroll
    for (int i = 0; i < 2; ++i)
#pragma unroll
        for (int j = 0; j < 4; ++j)
#pragma unroll
            for (int r = 0; r < 4; ++r)
                out[(size_t)(row0 + i * 16 + r) * N_DIM + (col0 + j * 16)] = acc[i][j][r];
}

extern "C" void kernel_launch(void* const* d_in, const int* in_sizes, int n_in,
                              void* d_out, int out_size, void* d_ws, size_t ws_size,
                              hipStream_t stream) {
    const float* x = (const float*)d_in[0];
    const float* w = (const float*)d_in[1];
    const float* u = (const float*)d_in[2];
    float* out = (float*)d_out;
    unsigned short* wb = (unsigned short*)d_ws;   // 512*4096*2 = 4 MB

    binarize_kernel<<<dim3(N_DIM * K_DIM / 4 / 256), dim3(256), 0, stream>>>(w, u, wb);

    gemm_bin_kernel<<<dim3((N_DIM / BN) * (M_DIM / BM)), dim3(THREADS), 0, stream>>>(x, wb, out);
}